// Round 5
// baseline (94.632 us; speedup 1.0000x reference)
//
#include <hip/hip_runtime.h>
#include <stdint.h>

#define IN_C 64
#define HH 256
#define WW 256
#define HW (HH * WW)
#define OUT_C 128
#define OH 254
#define OW 254
#define OHW (OH * OW)

// xb: bf16 [y][px][chunk] where chunk j' at pixel px holds channels 8*(j'^(px&7))..+7.
// The XOR swizzle is baked into the GLOBAL layout so conv can stage LDS as a verbatim
// linear global_load_lds copy (no padding allowed on that path) yet read B-frags
// conflict-free (bank-quad = (ch*4+quad)^((kx+nlane)&7) -> 2-way per phase = free).
#define XB_OFF 262144           // xb byte offset inside d_ws (wt occupies first 147456 B)
#define XROW 72                 // staged px per row: 72*128 B = 9216 B = 9 rounds of 1024
#define XRB (XROW * 128)

typedef __attribute__((ext_vector_type(4))) float f32x4;
typedef __attribute__((ext_vector_type(8))) __bf16 bf16x8;

__device__ __forceinline__ unsigned short f2bf(float f) {
  union { float f; unsigned u; } v; v.f = f;
  unsigned r = v.u + 0x7FFFu + ((v.u >> 16) & 1u);  // RNE
  return (unsigned short)(r >> 16);
}

__device__ __forceinline__ void async_lds16(const void* g, void* l) {
  __builtin_amdgcn_global_load_lds(
      (const __attribute__((address_space(1))) unsigned int*)g,
      (__attribute__((address_space(3))) unsigned int*)l, 16, 0, 0);
}

// Weights -> A-fragment order bf16 (unchanged from R4):
// wt[tap][ch][mt][lane][j] = bf16( W[o=mt*16+(lane&15)][c=ch*32+(lane>>4)*8+j][tap] )
__global__ void prep_w(const float* __restrict__ w, unsigned short* __restrict__ wt) {
  const int idx = blockIdx.x * 256 + threadIdx.x;
  if (idx >= 9 * 8192) return;
  const int j    = idx & 7;
  const int lane = (idx >> 3) & 63;
  const int mt   = (idx >> 9) & 7;
  const int ch   = (idx >> 12) & 1;
  const int tap  = idx >> 13;
  const int o = mt * 16 + (lane & 15);
  const int c = ch * 32 + (lane >> 4) * 8 + j;
  wt[idx] = f2bf(w[(o * IN_C + c) * 9 + tap]);
}

// x (fp32 CHW) -> xb (bf16, px-major, chunk-swizzled). One block per image row.
__global__ __launch_bounds__(256) void prep_x(const float* __restrict__ x,
                                              unsigned short* __restrict__ xb) {
  const int y = blockIdx.x;
  const int t = threadIdx.x;
  const int co = t & 7;   // channel chunk: c = co*8 + cc
  const int pg = t >> 3;  // px group: px = pg*8 + i
  const float* bx = x + (co * 8) * HW + y * WW + pg * 8;
  f32x4 v[8][2];
#pragma unroll
  for (int cc = 0; cc < 8; ++cc) {
    v[cc][0] = *(const f32x4*)(bx + cc * HW);
    v[cc][1] = *(const f32x4*)(bx + cc * HW + 4);
  }
#pragma unroll
  for (int i = 0; i < 8; ++i) {
    unsigned u[4];
#pragma unroll
    for (int p = 0; p < 4; ++p) {
      const float a = (i < 4) ? v[2 * p][0][i] : v[2 * p][1][i - 4];
      const float b = (i < 4) ? v[2 * p + 1][0][i] : v[2 * p + 1][1][i - 4];
      u[p] = (unsigned)f2bf(a) | ((unsigned)f2bf(b) << 16);
    }
    const int px = pg * 8 + i;
    *(uint4*)&xb[(((y * WW + px) * 8) + (co ^ i)) * 8] = make_uint4(u[0], u[1], u[2], u[3]);
  }
}

__global__ __launch_bounds__(256, 2) void conv_mfma(
    const unsigned short* __restrict__ xb, const unsigned short* __restrict__ wt,
    const float* __restrict__ bias, float* __restrict__ out) {
  __shared__ __align__(16) char Xs[4 * XRB];  // 36864 B, dense (global_load_lds target)

  const int tid  = threadIdx.x;
  const int wave = tid >> 6;
  const int lane = tid & 63;
  const int x0 = blockIdx.x * 64;   // 0,64,128,192 (last tile masks stores >= 254)
  const int y0 = blockIdx.y * 2;

  const int mhalf = wave & 1;
  const int nhalf = wave >> 1;
  const int nlane = lane & 15;
  const int quad  = lane >> 4;

  // A-frag chunk-0 prefetch first — in flight across staging
  const bf16x8* __restrict__ Wp = ((const bf16x8*)wt) + lane + (mhalf * 4) * 64;
  bf16x8 afA[4], afB[4];
#pragma unroll
  for (int mt = 0; mt < 4; ++mt) afA[mt] = Wp[mt * 64];

  // ---- stage 4 rows x 72 px: pure linear global->LDS DMA, 9 rounds per wave
  {
    const char* gb = (const char*)xb;
#pragma unroll
    for (int i = 0; i < 9; ++i) {
      const int c = wave + i * 4;          // 0..35
      const int r = c / 9;
      const int k = c - r * 9;
      async_lds16(gb + (size_t)((y0 + r) * WW + x0) * 128 + k * 1024 + lane * 16,
                  Xs + r * XRB + k * 1024);
    }
  }

  // accumulators init with bias (C/D row = quad*4+reg = out-ch)
  f32x4 acc[4][4];
#pragma unroll
  for (int mt = 0; mt < 4; ++mt) {
    const f32x4 bv = *(const f32x4*)(bias + (mhalf * 4 + mt) * 16 + quad * 4);
#pragma unroll
    for (int nt = 0; nt < 4; ++nt) acc[mt][nt] = bv;
  }

  __syncthreads();  // drains staging DMA (vmcnt) + single barrier of the kernel

  // ---- 9 taps x 2 ch-chunks, A prefetched one chunk ahead, all indices static
#pragma unroll 1
  for (int pair = 0; pair < 9; ++pair) {
    const int ky = pair / 3;
    const int kx = pair - ky * 3;
    const int r = nhalf + ky;
    const int sw = (kx + nlane) & 7;
    const char* xrow = Xs + r * XRB + (kx + nlane) * 128;
    const int j0 = (quad ^ sw) * 16;        // ch=0 chunk byte offset
    const int j1 = ((4 + quad) ^ sw) * 16;  // ch=1

#pragma unroll
    for (int mt = 0; mt < 4; ++mt) afB[mt] = Wp[((2 * pair + 1) * 8 + mt) * 64];

    {  // ch = 0 with afA
      bf16x8 bfr[4];
#pragma unroll
      for (int nt = 0; nt < 4; ++nt)
        bfr[nt] = *(const bf16x8*)(xrow + nt * 2048 + j0);
#pragma unroll
      for (int mt = 0; mt < 4; ++mt)
#pragma unroll
        for (int nt = 0; nt < 4; ++nt)
          acc[mt][nt] = __builtin_amdgcn_mfma_f32_16x16x32_bf16(afA[mt], bfr[nt], acc[mt][nt], 0, 0, 0);
    }

    if (pair < 8) {
#pragma unroll
      for (int mt = 0; mt < 4; ++mt) afA[mt] = Wp[((2 * pair + 2) * 8 + mt) * 64];
    }

    {  // ch = 1 with afB
      bf16x8 bfr[4];
#pragma unroll
      for (int nt = 0; nt < 4; ++nt)
        bfr[nt] = *(const bf16x8*)(xrow + nt * 2048 + j1);
#pragma unroll
      for (int mt = 0; mt < 4; ++mt)
#pragma unroll
        for (int nt = 0; nt < 4; ++nt)
          acc[mt][nt] = __builtin_amdgcn_mfma_f32_16x16x32_bf16(afB[mt], bfr[nt], acc[mt][nt], 0, 0, 0);
    }
  }

  // ---- epilogue (plain stores; OHW stride is non-pow2, no channel camping)
  const int y = y0 + nhalf;
#pragma unroll
  for (int mt = 0; mt < 4; ++mt) {
    const int obase = (mhalf * 4 + mt) * 16 + quad * 4;
#pragma unroll
    for (int nt = 0; nt < 4; ++nt) {
      const int xc = x0 + nt * 16 + nlane;
      if (xc < OW) {
        float* dst = out + obase * OHW + y * OW + xc;
#pragma unroll
        for (int reg = 0; reg < 4; ++reg)
          dst[reg * OHW] = acc[mt][nt][reg];
      }
    }
  }
}

extern "C" void kernel_launch(void* const* d_in, const int* in_sizes, int n_in,
                              void* d_out, int out_size, void* d_ws, size_t ws_size,
                              hipStream_t stream) {
  const float* x = (const float*)d_in[0];
  const float* w = (const float*)d_in[1];
  const float* b = (const float*)d_in[2];
  float* out = (float*)d_out;
  unsigned short* wt = (unsigned short*)d_ws;                       // 147456 B
  unsigned short* xb = (unsigned short*)((char*)d_ws + XB_OFF);     // 8.4 MB + slack
  // (last x-tile's staging reads run up to 16 px past row end -> xb has slack in ws;
  //  garbage only feeds masked output columns)

  prep_w<<<dim3(288), dim3(256), 0, stream>>>(w, wt);
  prep_x<<<dim3(256), dim3(256), 0, stream>>>(x, xb);
  conv_mfma<<<dim3(4, 127), dim3(256), 0, stream>>>(xb, wt, b, out);
}

// Round 6
// 88.515 us; speedup vs baseline: 1.0691x; 1.0691x over previous
//
#include <hip/hip_runtime.h>
#include <stdint.h>

#define IN_C 64
#define HH 256
#define WW 256
#define HW (HH * WW)
#define OUT_C 128
#define OH 254
#define OW 254
#define OHW (OH * OW)

#define XR 6     // staged input rows (4 out rows + 2 halo)
#define XW 66    // staged input width (64 + 2 halo)
#define CPAD 72  // channel stride in shorts: 144 B -> b128 B-frag reads bank-balanced

typedef __attribute__((ext_vector_type(4))) float f32x4;
typedef __attribute__((ext_vector_type(8))) __bf16 bf16x8;

__device__ __forceinline__ unsigned short f2bf(float f) {
  union { float f; unsigned u; } v; v.f = f;
  unsigned r = v.u + 0x7FFFu + ((v.u >> 16) & 1u);  // RNE (inputs finite/normal)
  return (unsigned short)(r >> 16);
}

// Weights -> A-fragment order bf16:
// wt[tap][ch][mt][lane][j] = bf16( W[o=mt*16+(lane&15)][c=ch*32+(lane>>4)*8+j][tap] )
// A-frag load is a verbatim per-lane global_load_dwordx4 (L1/L2-resident, no LDS).
__global__ void prep_w(const float* __restrict__ w, unsigned short* __restrict__ wt) {
  const int idx = blockIdx.x * 256 + threadIdx.x;
  if (idx >= 9 * 8192) return;
  const int j    = idx & 7;
  const int lane = (idx >> 3) & 63;
  const int mt   = (idx >> 9) & 7;
  const int ch   = (idx >> 12) & 1;
  const int tap  = idx >> 13;
  const int o = mt * 16 + (lane & 15);
  const int c = ch * 32 + (lane >> 4) * 8 + j;
  wt[idx] = f2bf(w[(o * IN_C + c) * 9 + tap]);
}

// 512-thread block: 4 output rows x 64 px x 128 ch. 8 waves = (row 0..3, mhalf 0..1).
// 6 staged input rows amortize the halo 1.5x (vs 2x at 2-row blocks); single barrier.
__global__ __launch_bounds__(512, 2) void conv_mfma(
    const float* __restrict__ x, const unsigned short* __restrict__ wt,
    const float* __restrict__ bias, float* __restrict__ out) {
  __shared__ __align__(16) unsigned short Xs[XR * XW * CPAD];  // 57024 B

  const int tid  = threadIdx.x;
  const int wave = tid >> 6;
  const int lane = tid & 63;
  const int x0 = blockIdx.x * 64;   // 0,64,128,192 (mask stores at xc >= 254)
  const int y0 = blockIdx.y * 4;    // 0..252 (mask stores at y >= 254)

  const int mhalf = wave & 1;   // half of the 128 out-channels
  const int row   = wave >> 1;  // which of the 4 output rows
  const int nlane = lane & 15;
  const int quad  = lane >> 4;

  // A-frag base; chunk-0 prefetch first — in flight across the staging phase
  const bf16x8* __restrict__ Wp = ((const bf16x8*)wt) + lane + (mhalf * 4) * 64;
  bf16x8 afA[4], afB[4];
#pragma unroll
  for (int mt = 0; mt < 4; ++mt) afA[mt] = Wp[mt * 64];

  // ---- stage Xs: Xs[r][xx][c] = bf16(x[c][y0+r][x0+xx])
  // thread = (cq 0..15, xh 0..15, rhalf 0..1); packed ds_write_b64 (4 ch per write):
  // 16 lanes of one xh-group cover all 32 banks; xh-groups alias 2-way = free.
  {
    const int cq = tid & 15;          // channels cq*4 .. cq*4+3
    const int xh = (tid >> 4) & 15;   // xx = xh*4 .. xh*4+3
    const int r3 = (tid >> 8) * 3;    // rows r3 .. r3+2
#pragma unroll
    for (int k = 0; k < 3; ++k) {
      const int r = r3 + k;
      const int yr = (y0 + r > 255) ? 255 : (y0 + r);  // clamp: only feeds masked rows
      const float* bx = x + yr * WW + x0 + xh * 4;
      f32x4 vv[4];
#pragma unroll
      for (int cc = 0; cc < 4; ++cc)
        vv[cc] = *(const f32x4*)(bx + (cq * 4 + cc) * HW);
#pragma unroll
      for (int xxi = 0; xxi < 4; ++xxi) {
        unsigned u0 = (unsigned)f2bf(vv[0][xxi]) | ((unsigned)f2bf(vv[1][xxi]) << 16);
        unsigned u1 = (unsigned)f2bf(vv[2][xxi]) | ((unsigned)f2bf(vv[3][xxi]) << 16);
        *(uint2*)&Xs[(r * XW + xh * 4 + xxi) * CPAD + cq * 4] = make_uint2(u0, u1);
      }
    }
    // tail halo xx = 64,65 : 6 rows x 2 px x 64 ch (clamped; feeds masked cols only)
    for (int k = tid; k < 768; k += 512) {
      const int c = k & 63;
      const int q = k >> 6;             // 0..11
      const int xxt = 64 + (q & 1);
      const int r = q >> 1;             // 0..5
      const int yr = (y0 + r > 255) ? 255 : (y0 + r);
      int xg = x0 + xxt;
      if (xg > WW - 1) xg = WW - 1;
      Xs[(r * XW + xxt) * CPAD + c] = f2bf(x[c * HW + yr * WW + xg]);
    }
  }

  // accumulators init with bias (C/D row = quad*4+reg = out-ch)
  f32x4 acc[4][4];
#pragma unroll
  for (int mt = 0; mt < 4; ++mt) {
    const f32x4 bv = *(const f32x4*)(bias + (mhalf * 4 + mt) * 16 + quad * 4);
#pragma unroll
    for (int nt = 0; nt < 4; ++nt) acc[mt][nt] = bv;
  }

  __syncthreads();  // Xs ready — the only barrier in the kernel

  // ---- 9 taps x 2 ch-chunks; A double-buffered one chunk ahead, all indices static
#pragma unroll 1
  for (int pair = 0; pair < 9; ++pair) {
    const int ky = pair / 3;
    const int kx = pair - ky * 3;
    const int r = row + ky;
    const unsigned short* xrow = &Xs[(r * XW + kx) * CPAD + quad * 8];

    // prefetch odd chunk (tap=pair, ch=1)
#pragma unroll
    for (int mt = 0; mt < 4; ++mt) afB[mt] = Wp[((2 * pair + 1) * 8 + mt) * 64];

    {  // compute even chunk (ch = 0) with afA
      bf16x8 bfr[4];
#pragma unroll
      for (int nt = 0; nt < 4; ++nt)
        bfr[nt] = *(const bf16x8*)&xrow[(nt * 16 + nlane) * CPAD];
#pragma unroll
      for (int mt = 0; mt < 4; ++mt)
#pragma unroll
        for (int nt = 0; nt < 4; ++nt)
          acc[mt][nt] = __builtin_amdgcn_mfma_f32_16x16x32_bf16(afA[mt], bfr[nt], acc[mt][nt], 0, 0, 0);
    }

    if (pair < 8) {  // prefetch next pair's even chunk
#pragma unroll
      for (int mt = 0; mt < 4; ++mt) afA[mt] = Wp[((2 * pair + 2) * 8 + mt) * 64];
    }

    {  // compute odd chunk (ch = 1) with afB
      bf16x8 bfr[4];
#pragma unroll
      for (int nt = 0; nt < 4; ++nt)
        bfr[nt] = *(const bf16x8*)&xrow[(nt * 16 + nlane) * CPAD + 32];
#pragma unroll
      for (int mt = 0; mt < 4; ++mt)
#pragma unroll
        for (int nt = 0; nt < 4; ++nt)
          acc[mt][nt] = __builtin_amdgcn_mfma_f32_16x16x32_bf16(afB[mt], bfr[nt], acc[mt][nt], 0, 0, 0);
    }
  }

  // ---- epilogue: C/D col = lane&15 (pixel), row = quad*4+reg (out-ch); plain stores
  const int y = y0 + row;
  if (y < OH) {
#pragma unroll
    for (int mt = 0; mt < 4; ++mt) {
      const int obase = (mhalf * 4 + mt) * 16 + quad * 4;
#pragma unroll
      for (int nt = 0; nt < 4; ++nt) {
        const int xc = x0 + nt * 16 + nlane;
        if (xc < OW) {
          float* dst = out + obase * OHW + y * OW + xc;
#pragma unroll
          for (int reg = 0; reg < 4; ++reg)
            dst[reg * OHW] = acc[mt][nt][reg];
        }
      }
    }
  }
}

extern "C" void kernel_launch(void* const* d_in, const int* in_sizes, int n_in,
                              void* d_out, int out_size, void* d_ws, size_t ws_size,
                              hipStream_t stream) {
  const float* x = (const float*)d_in[0];
  const float* w = (const float*)d_in[1];
  const float* b = (const float*)d_in[2];
  float* out = (float*)d_out;
  unsigned short* wt = (unsigned short*)d_ws;  // 147456 B fragment-ordered bf16 weights

  prep_w<<<dim3(288), dim3(256), 0, stream>>>(w, wt);
  conv_mfma<<<dim3(4, 64), dim3(512), 0, stream>>>(x, wt, b, out);
}